// Round 6
// baseline (158.181 us; speedup 1.0000x reference)
//
#include <hip/hip_runtime.h>

typedef __attribute__((ext_vector_type(8))) short bf16x8;
typedef __attribute__((ext_vector_type(4))) float f32x4;

#define NT 26
#define BROWS 8
#define NKS 18             // k-steps of 32; K total = 576 (560 real + 16 zero)
#define NGI 17             // gather instructions per block (136 quads / 8)
#define GBYTES (NGI * 1024)            // 17408 B staged fp32 gather area
#define HF_F (GBYTES / 4)              // float index of hf area
#define HSTR 36                        // hf row stride (dwords)
#define ZOFF_F (HF_F + BROWS * HSTR)   // float index of zero pad area (needs 16)
#define SMEM_F (ZOFF_F + 16)
#define Z1STR 68
#define WS_FRAG_DWORDS 18432   // 18 ks * 4 waves * 64 lanes * 8 bf16 / 2

__constant__ int c_OFFS[NT] = {
    0,1000001,1500002,1600003,1650004,1660005,1670006,1675007,1680008,1681009,
    1682010,1682511,1683012,1683113,1683214,1683265,1683316,1683337,1683358,
    1683369,1683380,1683386,1683392,1683396,1683400,1683403};

// flat quad list: c_QT[fq] = table | (quad<<8); padded cat col of quad fq = fq*4
__constant__ unsigned short c_QT[136] = {
  0,256,512,768,1024,1280,1536,1792,
  1,257,513,769,1025,1281,1537,1793,
  2,258,514,770,1026,1282,1538,1794,
  3,259,515,771,1027,1283,1539,1795,
  4,260,516,772,1028,1284,1540,1796,
  5,261,517,773,1029,1285,1541,1797,
  6,262,518,774,1030,1286,1542,1798,
  7,263,519,775,1031,1287,1543,1799,
  8,264,520,776,1032,1288,1544,1800,
  9,265,521,777,1033,1289,1545,1801,
  10,266,522,778,1034,1290,1546,1802,
  11,267,523,779,1035,1291,1547,1803,
  12,268,524,780,1036,1292,
  13,269,525,781,1037,1293,
  14,270,526,782,
  15,271,527,783,
  16,272,528,
  17,273,529,
  18,274,
  19,275,
  20,21,22,23,24,25,
  0,0,0,0};

// prep tables (padded col starts, true dims, true concat offsets) — unchanged
__constant__ int c_P_COLP[NT] = {
    0,32,64,96,128,160,192,224,256,288,320,352,384,408,432,448,464,476,
    488,496,504,508,512,516,520,524};
__constant__ int c_P_DIMS[NT] = {
    32,32,32,32,32,32,32,32,32,32,32,32,21,21,14,14,9,9,6,6,4,4,4,4,4,4};
__constant__ int c_P_COLF[NT] = {
    0,32,64,96,128,160,192,224,256,288,320,352,384,405,426,440,454,463,
    472,478,484,488,492,496,500,504};

__device__ __forceinline__ unsigned short f2bf(float f) {
  unsigned int u = __builtin_bit_cast(unsigned int, f);
  u += 0x7fffu + ((u >> 16) & 1u);       // RNE
  return (unsigned short)(u >> 16);
}

__device__ __forceinline__ unsigned cvtpk(float a, float b) {
  unsigned r;                             // lo = a, hi = b (RNE)
  asm("v_cvt_pk_bf16_f32 %0, %1, %2" : "=v"(r) : "v"(a), "v"(b));
  return r;
}

__device__ __forceinline__ float silu_f(float x) {
  return x / (1.0f + __expf(-x));
}

// ---- prep: W1 (fp32 [540][64]) -> bf16 MFMA B-fragments in ws (unchanged) ---
extern "C" __global__ void __launch_bounds__(256)
prep_w1(const float* __restrict__ W1, unsigned int* __restrict__ wsf) {
  const int g = blockIdx.x * 256 + threadIdx.x;   // output dword index
  if (g >= WS_FRAG_DWORDS) return;
  const int f  = g * 2;
  const int j  = f & 7;
  const int l  = (f >> 3) & 63;
  const int w  = (f >> 9) & 3;
  const int ks = f >> 11;
  const int bn = (w << 4) + (l & 15);
  const int k0 = (ks << 5) + ((l >> 4) << 3) + j;
  float v[2];
  #pragma unroll
  for (int e = 0; e < 2; ++e) {
    const int k = k0 + e;
    float x = 0.0f;
    if (k < 32) {
      x = W1[k * 64 + bn];                 // h block: W1 rows 0..31
    } else {
      const int c = k - 32;                // padded cat col
      for (int i = 0; i < NT; ++i) {
        const int off = c - c_P_COLP[i];
        if (off >= 0 && off < c_P_DIMS[i])
          x = W1[(32 + c_P_COLF[i] + off) * 64 + bn];
      }                                    // pad cols & c>=528 stay 0
    }
    v[e] = x;
  }
  wsf[g] = ((unsigned)f2bf(v[0])) | (((unsigned)f2bf(v[1])) << 16);
}

extern "C" __global__ void __launch_bounds__(256, 8)
tab_fused(const float* __restrict__ xc,   // [B,64]
          const int* __restrict__ xcat,   // [B,26]
          const float* __restrict__ emb,  // [TOTAL_ROWS,32]
          const float* __restrict__ Wc,   // [64,32]
          const float* __restrict__ bc,   // [32]
          const float* __restrict__ lng,  // [32]
          const float* __restrict__ lnb,  // [32]
          const unsigned short* __restrict__ wsf,  // W1 bf16 fragments
          const float* __restrict__ b1,   // [64]
          const float* __restrict__ W2,   // [64,32]
          const float* __restrict__ b2,   // [32]
          float* __restrict__ out) {      // [B,32]
  // [0, GBYTES): staged fp32 gather quads, layout [g][row][slot16B], slot = q^row
  //              (z1 fp32 [8][68] aliases here after the MFMA barrier)
  // [HF_F..): fp32 h [8][36];  [ZOFF_F..): 64 B zeros
  __shared__ __attribute__((aligned(16))) float smem[SMEM_F];

  const int t  = threadIdx.x;
  const int w  = t >> 6;          // wave id 0..3
  const int l  = t & 63;          // lane
  const int R0 = blockIdx.x * BROWS;

  const int bn = (w << 4) + (l & 15);   // output column owned by this lane
  const int kg = (l >> 4) << 3;         // k sub-offset within a k-step

  // ---------------- phase 1a: gather via global_load_lds ----------------------
  // Instruction g stages flat quads fq = g*8+(0..7) for 8 rows: lane = row*8+slot
  // holds quad (slot^row) -> LDS byte g*1024 + lane*16 (linear dest, swizzled src).
  {
    const int row  = l >> 3;
    const int slot = l & 7;
    const int qsw  = slot ^ row;
    #pragma unroll
    for (int g = 0; g < NGI; ++g) {
      if ((g & 3) == w) {
        const unsigned qt = c_QT[g * 8 + qsw];
        const int tab = qt & 255, q = qt >> 8;
        const int idx = xcat[(size_t)(R0 + row) * NT + tab];
        const float* src = emb + ((size_t)(c_OFFS[tab] + idx) << 5) + (q << 2);
        __builtin_amdgcn_global_load_lds(
            (const __attribute__((address_space(1))) void*)src,
            (__attribute__((address_space(3))) void*)((char*)smem + g * 1024),
            16, 0, 0);
      }
    }
  }

  // zero pad region (A-frag source for k >= 560)
  if (t < 16) smem[ZOFF_F + t] = 0.0f;

  // ---------------- phase 1b: cont MLP (1 output/thread) ----------------------
  {
    const int r = t >> 5, j = t & 31;
    const float* xr = xc + (size_t)(R0 + r) * 64;
    float h = bc[j];
    #pragma unroll 4
    for (int k4 = 0; k4 < 16; ++k4) {
      const float4 x4 = ((const float4*)xr)[k4];
      const float* wb = Wc + (k4 * 4) * 32 + j;
      h = __fmaf_rn(x4.x, wb[0],  h);
      h = __fmaf_rn(x4.y, wb[32], h);
      h = __fmaf_rn(x4.z, wb[64], h);
      h = __fmaf_rn(x4.w, wb[96], h);
    }
    float s1 = h, s2 = h * h;
    #pragma unroll
    for (int m = 1; m < 32; m <<= 1) {
      s1 += __shfl_xor(s1, m);
      s2 += __shfl_xor(s2, m);
    }
    const float mu = s1 * 0.03125f;
    const float var = s2 * 0.03125f - mu * mu;
    const float rs = rsqrtf(var + 1e-5f);
    smem[HF_F + r * HSTR + j] = silu_f((h - mu) * rs * lng[j] + lnb[j]);
  }
  __syncthreads();   // drains vmcnt (global_load_lds) + lgkm (hf writes)

  // ---------------- phase 2: MFMA over K=576 ----------------------------------
  f32x4 acc = (f32x4){0.f, 0.f, 0.f, 0.f};
  {
    const int rowA = l & 7;            // real rows 0..7 (frag rows 8..15 = dups)
    // gather-area chunk addrs: quad q0 = kg>>2 at slot q0^rowA, q0+1 at slot^1
    const char* a1 = (const char*)smem + rowA * 128 + ((kg >> 2) ^ rowA) * 16;
    const char* a2 = (const char*)smem + rowA * 128 + (((kg >> 2) ^ rowA) ^ 1) * 16;
    const float* hrow = smem + HF_F + rowA * HSTR + kg;
    const char* zb = (const char*)(smem + ZOFF_F);
    #pragma unroll
    for (int ks = 0; ks < NKS; ++ks) {
      const bf16x8 bw = *(const bf16x8*)(wsf + ((ks * 4 + w) * 64 + l) * 8);
      f32x4 lo, hi;
      if (ks == 0) {                       // h block
        lo = *(const f32x4*)hrow;
        hi = *(const f32x4*)(hrow + 4);
      } else if (ks == NKS - 1) {          // tail: kg>=16 -> zeros (k 560..575)
        const char* p1 = (kg >= 16) ? zb        : (a1 + (NKS - 2) * 1024);
        const char* p2 = (kg >= 16) ? (zb + 16) : (a2 + (NKS - 2) * 1024);
        lo = *(const f32x4*)p1;
        hi = *(const f32x4*)p2;
      } else {
        lo = *(const f32x4*)(a1 + (ks - 1) * 1024);
        hi = *(const f32x4*)(a2 + (ks - 1) * 1024);
      }
      uint4 u;
      u.x = cvtpk(lo.x, lo.y); u.y = cvtpk(lo.z, lo.w);
      u.z = cvtpk(hi.x, hi.y); u.w = cvtpk(hi.z, hi.w);
      const bf16x8 a = __builtin_bit_cast(bf16x8, u);
      acc = __builtin_amdgcn_mfma_f32_16x16x32_bf16(a, bw, acc, 0, 0, 0);
    }
  }
  __syncthreads();   // all MFMA reads done; safe to alias z1 onto gather area

  // ---------------- phase 2.5: z1 = silu(acc + b1) (rows 0..7 live in l<32) ---
  if (l < 32) {
    const float b1v = b1[bn];
    const int rb = (l >> 4) << 2;
    #pragma unroll
    for (int v = 0; v < 4; ++v)
      smem[(rb + v) * Z1STR + bn] = silu_f(acc[v] + b1v);
  }
  __syncthreads();

  // ---------------- phase 3: out = silu(z1 @ W2 + b2) -------------------------
  {
    const int r = t >> 5, j = t & 31;
    float a = b2[j];
    const float4* zr4 = (const float4*)(smem + r * Z1STR);
    #pragma unroll 4
    for (int k4 = 0; k4 < 16; ++k4) {
      const float4 zv = zr4[k4];
      const float* w2b = W2 + (k4 * 4) * 32 + j;
      a = __fmaf_rn(zv.x, w2b[0],  a);
      a = __fmaf_rn(zv.y, w2b[32], a);
      a = __fmaf_rn(zv.z, w2b[64], a);
      a = __fmaf_rn(zv.w, w2b[96], a);
    }
    out[(size_t)(R0 + r) * 32 + j] = silu_f(a);
  }
}

extern "C" void kernel_launch(void* const* d_in, const int* in_sizes, int n_in,
                              void* d_out, int out_size, void* d_ws, size_t ws_size,
                              hipStream_t stream) {
  const float* xc   = (const float*)d_in[0];
  const int*   xcat = (const int*)  d_in[1];
  const float* emb  = (const float*)d_in[2];
  const float* Wc   = (const float*)d_in[3];
  const float* bc   = (const float*)d_in[4];
  const float* lng  = (const float*)d_in[5];
  const float* lnb  = (const float*)d_in[6];
  const float* W1   = (const float*)d_in[7];
  const float* b1   = (const float*)d_in[8];
  const float* W2   = (const float*)d_in[9];
  const float* b2   = (const float*)d_in[10];
  float* out = (float*)d_out;

  unsigned int* wsf = (unsigned int*)d_ws;     // 73,728 B of W1 fragments
  hipLaunchKernelGGL(prep_w1, dim3((WS_FRAG_DWORDS + 255) / 256), dim3(256),
                     0, stream, W1, wsf);

  const int B = in_sizes[0] / 64;        // 131072
  const int grid = B / BROWS;            // 16384
  hipLaunchKernelGGL(tab_fused, dim3(grid), dim3(256), 0, stream,
                     xc, xcat, emb, Wc, bc, lng, lnb,
                     (const unsigned short*)wsf, b1, W2, b2, out);
}

// Round 8
// 112.755 us; speedup vs baseline: 1.4029x; 1.4029x over previous
//
#include <hip/hip_runtime.h>

typedef __attribute__((ext_vector_type(8))) short bf16x8;
typedef __attribute__((ext_vector_type(4))) float f32x4;

#define NT 26
#define BROWS 32
#define NKS 19             // k-steps of 32; K total = 608 (584 real + 24 zero)
#define LDSTR 616          // bf16 elems per tile row (608 + 8 slack); 1232 B stride
#define Z1STR 68           // fp32 z1 row stride (dwords)
#define WS_FRAG_DWORDS 19456   // 19 ks * 4 waves * 64 lanes * 8 bf16 / 2

__constant__ int c_OFFS[NT] = {
    0,1000001,1500002,1600003,1650004,1660005,1670006,1675007,1680008,1681009,
    1682010,1682511,1683012,1683113,1683214,1683265,1683316,1683337,1683358,
    1683369,1683380,1683386,1683392,1683396,1683400,1683403};

// prep tables: padded col starts (cat-relative), true dims, true concat offs
// padded widths: t0-13: 32 | t14-17: 16 | t18-19: 8 | t20-25: 4   (sum 552)
__constant__ int c_P_COLP[NT] = {
    0,32,64,96,128,160,192,224,256,288,320,352,384,416,448,464,480,496,
    512,520,528,532,536,540,544,548};
__constant__ int c_P_DIMS[NT] = {
    32,32,32,32,32,32,32,32,32,32,32,32,21,21,14,14,9,9,6,6,4,4,4,4,4,4};
__constant__ int c_P_COLF[NT] = {
    0,32,64,96,128,160,192,224,256,288,320,352,384,405,426,440,454,463,
    472,478,484,488,492,496,500,504};

__device__ __forceinline__ unsigned short f2bf(float f) {
  unsigned int u = __builtin_bit_cast(unsigned int, f);
  u += 0x7fffu + ((u >> 16) & 1u);       // RNE
  return (unsigned short)(u >> 16);
}

__device__ __forceinline__ unsigned cvtpk(float a, float b) {
  unsigned r;                             // lo = a, hi = b (RNE)
  asm("v_cvt_pk_bf16_f32 %0, %1, %2" : "=v"(r) : "v"(a), "v"(b));
  return r;
}

__device__ __forceinline__ uint2 pk2(float4 a) {
  uint2 o;
  o.x = cvtpk(a.x, a.y); o.y = cvtpk(a.z, a.w);
  return o;
}

__device__ __forceinline__ float silu_f(float x) {
  return x / (1.0f + __expf(-x));
}

// ---- prep: W1 (fp32 [540][64]) -> bf16 MFMA B-fragments (padded layout) ------
extern "C" __global__ void __launch_bounds__(256)
prep_w1(const float* __restrict__ W1, unsigned int* __restrict__ wsf) {
  const int g = blockIdx.x * 256 + threadIdx.x;   // output dword index
  if (g >= WS_FRAG_DWORDS) return;
  const int f  = g * 2;
  const int j  = f & 7;
  const int l  = (f >> 3) & 63;
  const int w  = (f >> 9) & 3;
  const int ks = f >> 11;
  const int bn = (w << 4) + (l & 15);
  const int k0 = (ks << 5) + ((l >> 4) << 3) + j;
  float v[2];
  #pragma unroll
  for (int e = 0; e < 2; ++e) {
    const int k = k0 + e;
    float x = 0.0f;
    if (k < 32) {
      x = W1[k * 64 + bn];                 // h block: W1 rows 0..31
    } else {
      const int c = k - 32;                // padded cat col (0..575)
      for (int i = 0; i < NT; ++i) {
        const int off = c - c_P_COLP[i];
        if (off >= 0 && off < c_P_DIMS[i])
          x = W1[(32 + c_P_COLF[i] + off) * 64 + bn];
      }                                    // pad cols & c>=552 stay 0
    }
    v[e] = x;
  }
  wsf[g] = ((unsigned)f2bf(v[0])) | (((unsigned)f2bf(v[1])) << 16);
}

extern "C" __global__ void __launch_bounds__(256, 2)
tab_fused(const float* __restrict__ xc,   // [B,64]
          const int* __restrict__ xcat,   // [B,26]
          const float* __restrict__ emb,  // [TOTAL_ROWS,32]
          const float* __restrict__ Wc,   // [64,32]
          const float* __restrict__ bc,   // [32]
          const float* __restrict__ lng,  // [32]
          const float* __restrict__ lnb,  // [32]
          const unsigned short* __restrict__ wsf,  // W1 bf16 fragments
          const float* __restrict__ b1,   // [64]
          const float* __restrict__ W2,   // [64,32]
          const float* __restrict__ b2,   // [32]
          float* __restrict__ out) {      // [B,32]
  // bf16 tile [32][LDSTR] during phases 1-2; z1 (fp32 [32][Z1STR]) aliases after.
  __shared__ __attribute__((aligned(16))) float smem[(BROWS * LDSTR) / 2]; // 39,424 B
  __shared__ __attribute__((aligned(16))) int xs[BROWS * NT];              //  3,328 B
  unsigned short* fused = (unsigned short*)smem;
  char* tbb = (char*)smem;
  float* z1 = smem;

  const int t  = threadIdx.x;
  const int w  = t >> 6;          // wave id 0..3
  const int l  = t & 63;          // lane
  const int R0 = blockIdx.x * BROWS;

  const int bn = (w << 4) + (l & 15);   // output column owned by this lane
  const int kg = (l >> 4) << 3;         // k sub-offset within a k-step

  // ---------------- phase 0a: stage xcat tile (coalesced) + zero tail ---------
  if (t < 208) ((int4*)xs)[t] = ((const int4*)(xcat + (size_t)R0 * NT))[t];
  if (t >= 160) {                       // 96 threads zero cols 584..607 (48 B/row)
    const int tt = t - 160;
    uint4 zz = {0u, 0u, 0u, 0u};
    *(uint4*)(tbb + (tt / 3) * (LDSTR * 2) + 1168 + (tt % 3) * 16) = zz;
  }
  __syncthreads();

  // ---------------- phase 1a: lane-cooperative gather (coalesced) -------------
  // Class A (tables 0..13, 8 quads/row): 8 lanes load one row's 128 B contig.
  const int rowA = (w << 3) + (l >> 3);   // this lane's row for ALL class-A insts
  const int qA = l & 7;
  float4 vA[14];
  #pragma unroll
  for (int u = 0; u < 14; ++u) {
    const int idx = xs[rowA * NT + u];
    vA[u] = *(const float4*)(emb + ((size_t)(c_OFFS[u] + idx) << 5) + (qA << 2));
  }
  // Class B (tables 14..17, 4 quads): 4 lanes per row.
  const int pbb = (w << 4) + (l >> 2);    // 0..63
  const int rowB = pbb & 31;
  const int qB = l & 3;
  float4 vB[2];
  #pragma unroll
  for (int u = 0; u < 2; ++u) {
    const int tab = 14 + (u << 1) + (pbb >> 5);
    const int idx = xs[rowB * NT + tab];
    vB[u] = *(const float4*)(emb + ((size_t)(c_OFFS[tab] + idx) << 5) + (qB << 2));
  }
  // Class C (tables 18,19, 2 quads): 2 lanes per row; waves 0,1 only.
  const bool hasC = (w < 2);
  const int rowC = l >> 1, qC = l & 1, tabC = 18 + w;
  float4 vC = {0.f, 0.f, 0.f, 0.f};
  if (hasC) {
    const int idx = xs[rowC * NT + tabC];
    vC = *(const float4*)(emb + ((size_t)(c_OFFS[tabC] + idx) << 5) + (qC << 2));
  }
  // Class D (tables 20..25, 1 quad): 1 lane per row; waves 0,2,3.
  const bool hasD = (w != 1);
  const int dD = (w == 2) ? 0 : ((w == 3) ? 1 : 2);
  const int tabD = 20 + (dD << 1) + (l >> 5);
  const int rowD = l & 31;
  float4 vD = {0.f, 0.f, 0.f, 0.f};
  if (hasD) {
    const int idx = xs[rowD * NT + tabD];
    vD = *(const float4*)(emb + ((size_t)(c_OFFS[tabD] + idx) << 5));
  }

  // ---------------- phase 1b: cont MLP -> bf16 into tile cols 0..31 -----------
  {
    const int r  = t >> 3;
    const int j0 = (t & 7) << 2;
    const float* xr = xc + (size_t)(R0 + r) * 64;
    float h0 = bc[j0], h1 = bc[j0 + 1], h2 = bc[j0 + 2], h3 = bc[j0 + 3];
    #pragma unroll 4
    for (int k4 = 0; k4 < 16; ++k4) {
      const float4 x4 = ((const float4*)xr)[k4];
      const float* wb = Wc + (k4 * 4) * 32 + j0;
      const float4 w0 = *(const float4*)(wb);
      const float4 w1 = *(const float4*)(wb + 32);
      const float4 w2 = *(const float4*)(wb + 64);
      const float4 w3 = *(const float4*)(wb + 96);
      h0 = __fmaf_rn(x4.x, w0.x, h0); h1 = __fmaf_rn(x4.x, w0.y, h1);
      h2 = __fmaf_rn(x4.x, w0.z, h2); h3 = __fmaf_rn(x4.x, w0.w, h3);
      h0 = __fmaf_rn(x4.y, w1.x, h0); h1 = __fmaf_rn(x4.y, w1.y, h1);
      h2 = __fmaf_rn(x4.y, w1.z, h2); h3 = __fmaf_rn(x4.y, w1.w, h3);
      h0 = __fmaf_rn(x4.z, w2.x, h0); h1 = __fmaf_rn(x4.z, w2.y, h1);
      h2 = __fmaf_rn(x4.z, w2.z, h2); h3 = __fmaf_rn(x4.z, w2.w, h3);
      h0 = __fmaf_rn(x4.w, w3.x, h0); h1 = __fmaf_rn(x4.w, w3.y, h1);
      h2 = __fmaf_rn(x4.w, w3.z, h2); h3 = __fmaf_rn(x4.w, w3.w, h3);
    }
    float s1v = h0 + h1 + h2 + h3;
    float s2v = h0 * h0 + h1 * h1 + h2 * h2 + h3 * h3;
    #pragma unroll
    for (int m = 1; m < 8; m <<= 1) {
      s1v += __shfl_xor(s1v, m);
      s2v += __shfl_xor(s2v, m);
    }
    const float mu = s1v * 0.03125f;
    const float var = s2v * 0.03125f - mu * mu;
    const float rs = rsqrtf(var + 1e-5f);
    const float g0 = silu_f((h0 - mu) * rs * lng[j0]     + lnb[j0]);
    const float g1 = silu_f((h1 - mu) * rs * lng[j0 + 1] + lnb[j0 + 1]);
    const float g2 = silu_f((h2 - mu) * rs * lng[j0 + 2] + lnb[j0 + 2]);
    const float g3 = silu_f((h3 - mu) * rs * lng[j0 + 3] + lnb[j0 + 3]);
    uint2 hw;
    hw.x = cvtpk(g0, g1);
    hw.y = cvtpk(g2, g3);
    *(uint2*)(tbb + r * (LDSTR * 2) + j0 * 2) = hw;
  }

  // ---------------- phase 1c: convert + write gathered quads ------------------
  {
    // A: col = 32 + u*32 + qA*4  -> byte = 64 + u*64 + qA*8
    char* dA = tbb + rowA * (LDSTR * 2) + 64 + qA * 8;
    #pragma unroll
    for (int u = 0; u < 14; ++u) *(uint2*)(dA + u * 64) = pk2(vA[u]);
    // B: col = 480 + ((u<<1)+(pbb>>5))*16 + qB*4 -> byte = 960 + ... *32 + qB*8
    char* dB = tbb + rowB * (LDSTR * 2) + 960 + (pbb >> 5) * 32 + qB * 8;
    #pragma unroll
    for (int u = 0; u < 2; ++u) *(uint2*)(dB + u * 64) = pk2(vB[u]);
    // C: col = 544 + w*8 + qC*4 -> byte = 1088 + w*16 + qC*8
    if (hasC)
      *(uint2*)(tbb + rowC * (LDSTR * 2) + 1088 + w * 16 + qC * 8) = pk2(vC);
    // D: col = 560 + (2*dD + l>>5)*4 -> byte = 1120 + (2*dD + l>>5)*8
    if (hasD)
      *(uint2*)(tbb + rowD * (LDSTR * 2) + 1120 +
                (((dD << 1) + (l >> 5)) << 3)) = pk2(vD);
  }

  // ---------------- phase 0b (late): all 19 B-fragment k-steps from ws --------
  bf16x8 bfw[NKS];
  #pragma unroll
  for (int ks = 0; ks < NKS; ++ks)
    bfw[ks] = *(const bf16x8*)(wsf + ((ks * 4 + w) * 64 + l) * 8);
  __syncthreads();

  // ---------------- phase 2: MFMA over K=608 ----------------------------------
  f32x4 acc[2];
  acc[0] = (f32x4){0.f, 0.f, 0.f, 0.f};
  acc[1] = (f32x4){0.f, 0.f, 0.f, 0.f};
  const unsigned short* arow0 = &fused[(l & 15) * LDSTR + kg];
  const unsigned short* arow1 = arow0 + 16 * LDSTR;
  #pragma unroll
  for (int ks = 0; ks < NKS; ++ks) {
    acc[0] = __builtin_amdgcn_mfma_f32_16x16x32_bf16(
        *(const bf16x8*)(arow0 + (ks << 5)), bfw[ks], acc[0], 0, 0, 0);
    acc[1] = __builtin_amdgcn_mfma_f32_16x16x32_bf16(
        *(const bf16x8*)(arow1 + (ks << 5)), bfw[ks], acc[1], 0, 0, 0);
  }
  __syncthreads();   // all MFMA reads done; safe to alias z1 onto the tile

  // ---------------- phase 2.5: z1 = silu(acc + b1) ----------------------------
  {
    const float b1v = b1[bn];
    const int rb = (l >> 4) << 2;
    #pragma unroll
    for (int mt = 0; mt < 2; ++mt) {
      #pragma unroll
      for (int v = 0; v < 4; ++v) {
        const int row = (mt << 4) + rb + v;      // C/D layout: row=(l>>4)*4+reg
        z1[row * Z1STR + bn] = silu_f(acc[mt][v] + b1v);
      }
    }
  }
  __syncthreads();

  // ---------------- phase 3: out = silu(z1 @ W2 + b2) -------------------------
  {
    const int r  = t >> 3;            // 8 threads per row
    const int j0 = (t & 7) << 2;      // 4 output cols each
    float a0 = b2[j0], a1 = b2[j0 + 1], a2 = b2[j0 + 2], a3 = b2[j0 + 3];
    const float4* zr4 = (const float4*)&z1[r * Z1STR];
    #pragma unroll
    for (int k4 = 0; k4 < 16; ++k4) {
      const float4 zv = zr4[k4];
      const float* w2b = W2 + (k4 * 4) * 32 + j0;
      const float4 w0 = *(const float4*)(w2b);
      const float4 w1 = *(const float4*)(w2b + 32);
      const float4 w2v = *(const float4*)(w2b + 64);
      const float4 w3 = *(const float4*)(w2b + 96);
      a0 = __fmaf_rn(zv.x, w0.x, a0); a1 = __fmaf_rn(zv.x, w0.y, a1);
      a2 = __fmaf_rn(zv.x, w0.z, a2); a3 = __fmaf_rn(zv.x, w0.w, a3);
      a0 = __fmaf_rn(zv.y, w1.x, a0); a1 = __fmaf_rn(zv.y, w1.y, a1);
      a2 = __fmaf_rn(zv.y, w1.z, a2); a3 = __fmaf_rn(zv.y, w1.w, a3);
      a0 = __fmaf_rn(zv.z, w2v.x, a0); a1 = __fmaf_rn(zv.z, w2v.y, a1);
      a2 = __fmaf_rn(zv.z, w2v.z, a2); a3 = __fmaf_rn(zv.z, w2v.w, a3);
      a0 = __fmaf_rn(zv.w, w3.x, a0); a1 = __fmaf_rn(zv.w, w3.y, a1);
      a2 = __fmaf_rn(zv.w, w3.z, a2); a3 = __fmaf_rn(zv.w, w3.w, a3);
    }
    float4 o;
    o.x = silu_f(a0); o.y = silu_f(a1); o.z = silu_f(a2); o.w = silu_f(a3);
    *(float4*)(out + (size_t)(R0 + r) * 32 + j0) = o;
  }
}

extern "C" void kernel_launch(void* const* d_in, const int* in_sizes, int n_in,
                              void* d_out, int out_size, void* d_ws, size_t ws_size,
                              hipStream_t stream) {
  const float* xc   = (const float*)d_in[0];
  const int*   xcat = (const int*)  d_in[1];
  const float* emb  = (const float*)d_in[2];
  const float* Wc   = (const float*)d_in[3];
  const float* bc   = (const float*)d_in[4];
  const float* lng  = (const float*)d_in[5];
  const float* lnb  = (const float*)d_in[6];
  const float* W1   = (const float*)d_in[7];
  const float* b1   = (const float*)d_in[8];
  const float* W2   = (const float*)d_in[9];
  const float* b2   = (const float*)d_in[10];
  float* out = (float*)d_out;

  unsigned int* wsf = (unsigned int*)d_ws;     // 77,824 B of W1 fragments
  hipLaunchKernelGGL(prep_w1, dim3((WS_FRAG_DWORDS + 255) / 256), dim3(256),
                     0, stream, W1, wsf);

  const int B = in_sizes[0] / 64;        // 131072
  const int grid = B / BROWS;            // 4096
  hipLaunchKernelGGL(tab_fused, dim3(grid), dim3(256), 0, stream,
                     xc, xcat, emb, Wc, bc, lng, lnb,
                     (const unsigned short*)wsf, b1, W2, b2, out);
}